// Round 1
// baseline (1824.823 us; speedup 1.0000x reference)
//
#include <hip/hip_runtime.h>
#include <hip/hip_bf16.h>
#include <math.h>

#define N_NODES   100000
#define F_IN      1433
#define H_DIM     16
#define C_DIM     7
#define NGRAPHS   64
#define GPOOL     (NGRAPHS * C_DIM)   // 448
#define SCAN_CHUNK 1024

// ---------- helpers ----------
__device__ __forceinline__ unsigned float_key(float f) {
    unsigned b = __float_as_uint(f);
    return (b & 0x80000000u) ? ~b : (b | 0x80000000u);
}
__device__ __forceinline__ float key_float(unsigned u) {
    unsigned b = (u & 0x80000000u) ? (u ^ 0x80000000u) : ~u;
    return __uint_as_float(b);
}

// ---------- in-degree count (int atomics), deg pre-zeroed ----------
__global__ void k_deg(const int* __restrict__ dst, int* __restrict__ deg, int E) {
    int i = blockIdx.x * 256 + threadIdx.x;
    if (i < E) atomicAdd(&deg[dst[i]], 1);
}

// ---------- exclusive scan of deg -> cursor (3 kernels) ----------
__global__ void k_scan_block(const int* __restrict__ deg, int* __restrict__ cursor,
                             int* __restrict__ bsum, int n) {
    __shared__ int sh[256];
    int base = blockIdx.x * SCAN_CHUNK + threadIdx.x * 4;
    int v[4]; int sum = 0;
    #pragma unroll
    for (int j = 0; j < 4; ++j) { int idx = base + j; v[j] = (idx < n) ? deg[idx] : 0; sum += v[j]; }
    sh[threadIdx.x] = sum;
    __syncthreads();
    for (int off = 1; off < 256; off <<= 1) {
        int t = (threadIdx.x >= off) ? sh[threadIdx.x - off] : 0;
        __syncthreads();
        sh[threadIdx.x] += t;
        __syncthreads();
    }
    int excl = (threadIdx.x > 0) ? sh[threadIdx.x - 1] : 0;
    if (threadIdx.x == 255) bsum[blockIdx.x] = sh[255];
    int run = excl;
    #pragma unroll
    for (int j = 0; j < 4; ++j) { int idx = base + j; if (idx < n) cursor[idx] = run; run += v[j]; }
}

__global__ void k_scan_top(int* __restrict__ bsum, int nb) {
    __shared__ int sh[128];
    int v = (threadIdx.x < nb) ? bsum[threadIdx.x] : 0;
    sh[threadIdx.x] = v;
    __syncthreads();
    for (int off = 1; off < 128; off <<= 1) {
        int t = (threadIdx.x >= off) ? sh[threadIdx.x - off] : 0;
        __syncthreads();
        sh[threadIdx.x] += t;
        __syncthreads();
    }
    if (threadIdx.x < nb) bsum[threadIdx.x] = (threadIdx.x > 0) ? sh[threadIdx.x - 1] : 0;
}

__global__ void k_scan_add(int* __restrict__ cursor, const int* __restrict__ bsum, int n) {
    int i = blockIdx.x * 256 + threadIdx.x;
    if (i < n) cursor[i] += bsum[i >> 10];
}

// ---------- CSR fill: cursor mutates from start-offset to end-offset ----------
__global__ void k_fill(const int* __restrict__ ei, int* __restrict__ cursor,
                       int* __restrict__ csr, int E) {
    int e = blockIdx.x * 256 + threadIdx.x;
    if (e < E) {
        int s = ei[e], d = ei[E + e];
        int pos = atomicAdd(&cursor[d], 1);
        csr[pos] = s;
    }
}

// inv = rsqrt(deg + 1)
__global__ void k_inv(const int* __restrict__ deg, float* __restrict__ inv, int n) {
    int i = blockIdx.x * 256 + threadIdx.x;
    if (i < n) inv[i] = rsqrtf((float)deg[i] + 1.0f);
}

// ---------- GEMM1: hs1[i][:] = (x[i,:] @ W1) * inv[i] ----------
__global__ __launch_bounds__(256) void k_gemm1(const float* __restrict__ x,
                                               const float* __restrict__ W1,
                                               const float* __restrict__ inv,
                                               float* __restrict__ hs1) {
    __shared__ float xT[32 * 258];
    __shared__ float wt[32 * 16];
    const int tid = threadIdx.x;
    const int r0  = blockIdx.x * 256;
    const int rg  = tid >> 2;
    const int cg  = tid & 3;
    float acc[4][4] = {};

    for (int f0 = 0; f0 < F_IN; f0 += 32) {
        #pragma unroll
        for (int it = 0; it < 32; ++it) {
            int lin = it * 256 + tid;
            int r = lin >> 5, c = lin & 31;
            int row = r0 + r, f = f0 + c;
            float v = 0.0f;
            if (row < N_NODES && f < F_IN) v = x[(size_t)row * F_IN + f];
            xT[c * 258 + r] = v;
        }
        #pragma unroll
        for (int it = 0; it < 2; ++it) {
            int lin = it * 256 + tid;
            int f = f0 + (lin >> 4);
            wt[lin] = (f < F_IN) ? W1[f * 16 + (lin & 15)] : 0.0f;
        }
        __syncthreads();

        #pragma unroll
        for (int ff = 0; ff < 32; ++ff) {
            const float2* xf2 = (const float2*)&xT[ff * 258];
            float2 a01 = xf2[rg * 2];
            float2 a23 = xf2[rg * 2 + 1];
            float4 wv  = *(const float4*)&wt[ff * 16 + cg * 4];
            float xa[4] = {a01.x, a01.y, a23.x, a23.y};
            #pragma unroll
            for (int i2 = 0; i2 < 4; ++i2) {
                acc[i2][0] = fmaf(xa[i2], wv.x, acc[i2][0]);
                acc[i2][1] = fmaf(xa[i2], wv.y, acc[i2][1]);
                acc[i2][2] = fmaf(xa[i2], wv.z, acc[i2][2]);
                acc[i2][3] = fmaf(xa[i2], wv.w, acc[i2][3]);
            }
        }
        __syncthreads();
    }

    #pragma unroll
    for (int i2 = 0; i2 < 4; ++i2) {
        int row = r0 + rg * 4 + i2;
        if (row < N_NODES) {
            float s = inv[row];
            float4 v;
            v.x = acc[i2][0] * s; v.y = acc[i2][1] * s;
            v.z = acc[i2][2] * s; v.w = acc[i2][3] * s;
            *(float4*)&hs1[(size_t)row * 16 + cg * 4] = v;
        }
    }
}

// ---------- layer1 gather + relu + layer2 linear ----------
// Restructured: 64 nodes/block, 4 lanes/node, float4 gathers, 4-deep csr pipeline.
// Same bytes moved, ~4x fewer VMEM instructions, 4 edges of gathers in flight.
__global__ __launch_bounds__(256) void k_agg1(const float* __restrict__ hs1,
                                              const int* __restrict__ cursor,
                                              const int* __restrict__ deg,
                                              const int* __restrict__ csr,
                                              const float* __restrict__ inv,
                                              const float* __restrict__ b1,
                                              const float* __restrict__ W2,
                                              float* __restrict__ hs2, int n) {
    __shared__ float sh[64][17];
    __shared__ float sW[112];
    __shared__ float sb[16];
    if (threadIdx.x < 112) sW[threadIdx.x] = W2[threadIdx.x];
    if (threadIdx.x < 16)  sb[threadIdx.x] = b1[threadIdx.x];
    __syncthreads();
    const int nl = threadIdx.x >> 2;      // node lane 0..63
    const int fq = threadIdx.x & 3;       // feature quad 0..3
    const int i = blockIdx.x * 64 + nl;
    if (i < n) {
        // self-loop (hs1 rows are pre-scaled by inv[src])
        float4 acc = *(const float4*)&hs1[(size_t)i * 16 + fq * 4];
        const int en = cursor[i];
        int j = en - deg[i];
        for (; j + 4 <= en; j += 4) {
            int s0 = csr[j], s1 = csr[j + 1], s2 = csr[j + 2], s3 = csr[j + 3];
            float4 v0 = *(const float4*)&hs1[(size_t)s0 * 16 + fq * 4];
            float4 v1 = *(const float4*)&hs1[(size_t)s1 * 16 + fq * 4];
            float4 v2 = *(const float4*)&hs1[(size_t)s2 * 16 + fq * 4];
            float4 v3 = *(const float4*)&hs1[(size_t)s3 * 16 + fq * 4];
            acc.x += (v0.x + v1.x) + (v2.x + v3.x);
            acc.y += (v0.y + v1.y) + (v2.y + v3.y);
            acc.z += (v0.z + v1.z) + (v2.z + v3.z);
            acc.w += (v0.w + v1.w) + (v2.w + v3.w);
        }
        for (; j < en; ++j) {
            int s2i = csr[j];
            float4 v = *(const float4*)&hs1[(size_t)s2i * 16 + fq * 4];
            acc.x += v.x; acc.y += v.y; acc.z += v.z; acc.w += v.w;
        }
        float s = inv[i];
        sh[nl][fq * 4 + 0] = fmaxf(fmaf(acc.x, s, sb[fq * 4 + 0]), 0.0f);
        sh[nl][fq * 4 + 1] = fmaxf(fmaf(acc.y, s, sb[fq * 4 + 1]), 0.0f);
        sh[nl][fq * 4 + 2] = fmaxf(fmaf(acc.z, s, sb[fq * 4 + 2]), 0.0f);
        sh[nl][fq * 4 + 3] = fmaxf(fmaf(acc.w, s, sb[fq * 4 + 3]), 0.0f);
    }
    __syncthreads();
    // h @ W2 (16 -> 7), 448 outputs per block
    for (int t = threadIdx.x; t < 64 * 7; t += 256) {
        int nl2 = t / 7, k = t % 7;
        int i2 = blockIdx.x * 64 + nl2;
        if (i2 < n) {
            float o = 0.0f;
            #pragma unroll
            for (int j = 0; j < 16; ++j) o = fmaf(sh[nl2][j], sW[j * 7 + k], o);
            hs2[(size_t)i2 * 7 + k] = o * inv[i2];
        }
    }
}

// ---------- layer2 gather + bias + log_softmax + graph max-pool ----------
// 32 nodes/block, 8 threads/node (7 active). 4-deep csr pipeline.
__global__ __launch_bounds__(256) void k_agg2(const float* __restrict__ hs2,
                                              const int* __restrict__ cursor,
                                              const int* __restrict__ deg,
                                              const int* __restrict__ csr,
                                              const float* __restrict__ inv,
                                              const float* __restrict__ b2,
                                              const int* __restrict__ batch,
                                              float* __restrict__ out,
                                              unsigned* __restrict__ gkeys, int n) {
    __shared__ unsigned lmax[GPOOL];
    for (int t = threadIdx.x; t < GPOOL; t += 256) lmax[t] = 0u;
    __syncthreads();
    const int nl = threadIdx.x >> 3, k = threadIdx.x & 7;
    const int i = blockIdx.x * 32 + nl;
    if (i < n) {
        float z = -INFINITY;
        if (k < 7) {
            float acc = hs2[(size_t)i * 7 + k];    // self-loop (pre-scaled)
            const int en = cursor[i];
            int j = en - deg[i];
            for (; j + 4 <= en; j += 4) {
                int s0 = csr[j], s1 = csr[j + 1], s2 = csr[j + 2], s3 = csr[j + 3];
                float a0 = hs2[(size_t)s0 * 7 + k];
                float a1 = hs2[(size_t)s1 * 7 + k];
                float a2 = hs2[(size_t)s2 * 7 + k];
                float a3 = hs2[(size_t)s3 * 7 + k];
                acc += (a0 + a1) + (a2 + a3);
            }
            for (; j < en; ++j) acc += hs2[(size_t)csr[j] * 7 + k];
            z = fmaf(acc, inv[i], b2[k]);
        }
        float m = z;
        #pragma unroll
        for (int off = 4; off >= 1; off >>= 1) m = fmaxf(m, __shfl_xor(m, off, 8));
        float e = (k < 7) ? expf(z - m) : 0.0f;
        float ssum = e;
        #pragma unroll
        for (int off = 4; off >= 1; off >>= 1) ssum += __shfl_xor(ssum, off, 8);
        float l = logf(ssum);
        if (k < 7) {
            out[GPOOL + (size_t)i * 7 + k] = z - m - l;
            int b = batch[i];
            atomicMax(&lmax[b * 7 + k], float_key(z));
        }
    }
    __syncthreads();
    for (int t = threadIdx.x; t < GPOOL; t += 256) {
        unsigned v = lmax[t];
        if (v) atomicMax(&gkeys[t], v);
    }
}

__global__ void k_decode(const unsigned* __restrict__ gkeys, float* __restrict__ out) {
    int t = blockIdx.x * 64 + threadIdx.x;
    if (t < GPOOL) out[t] = key_float(gkeys[t]);
}

extern "C" void kernel_launch(void* const* d_in, const int* in_sizes, int n_in,
                              void* d_out, int out_size, void* d_ws, size_t ws_size,
                              hipStream_t stream) {
    const float* x    = (const float*)d_in[0];
    const int*   ei   = (const int*)d_in[1];
    const int*   batch= (const int*)d_in[2];
    const float* W1   = (const float*)d_in[3];
    const float* b1   = (const float*)d_in[4];
    const float* W2   = (const float*)d_in[5];
    const float* b2   = (const float*)d_in[6];
    float* out = (float*)d_out;
    const int E = in_sizes[1] / 2;
    const int n = in_sizes[0] / F_IN;
    const int nb = (n + SCAN_CHUNK - 1) / SCAN_CHUNK;   // 98

    // workspace: deg(int n) | cursor(int n) | bsum(int 128) | csr(int E) |
    //            inv(f n) | hs1(f 16n) | hs2(f 7n) | gkeys(u32 448)
    int* deg    = (int*)d_ws;
    int* cursor = deg + n;
    int* bsum   = cursor + n;
    int* csr    = bsum + 128;
    float* inv  = (float*)(csr + E);
    float* hs1  = inv + n;
    float* hs2  = hs1 + (size_t)n * 16;
    unsigned* gkeys = (unsigned*)(hs2 + (size_t)n * 7);

    hipMemsetAsync(deg, 0, (size_t)n * sizeof(int), stream);
    hipMemsetAsync(gkeys, 0, GPOOL * sizeof(unsigned), stream);

    k_deg<<<(E + 255) / 256, 256, 0, stream>>>(ei + E, deg, E);
    k_scan_block<<<nb, 256, 0, stream>>>(deg, cursor, bsum, n);
    k_scan_top<<<1, 128, 0, stream>>>(bsum, nb);
    k_scan_add<<<(n + 255) / 256, 256, 0, stream>>>(cursor, bsum, n);
    k_fill<<<(E + 255) / 256, 256, 0, stream>>>(ei, cursor, csr, E);
    k_inv<<<(n + 255) / 256, 256, 0, stream>>>(deg, inv, n);
    k_gemm1<<<(n + 255) / 256, 256, 0, stream>>>(x, W1, inv, hs1);
    k_agg1<<<(n + 63) / 64, 256, 0, stream>>>(hs1, cursor, deg, csr, inv, b1, W2, hs2, n);
    k_agg2<<<(n + 31) / 32, 256, 0, stream>>>(hs2, cursor, deg, csr, inv, b2, batch, out, gkeys, n);
    k_decode<<<7, 64, 0, stream>>>(gkeys, out);
}

// Round 2
// 1771.853 us; speedup vs baseline: 1.0299x; 1.0299x over previous
//
#include <hip/hip_runtime.h>
#include <hip/hip_bf16.h>
#include <math.h>

#define N_NODES   100000
#define F_IN      1433
#define H_DIM     16
#define C_DIM     7
#define NGRAPHS   64
#define GPOOL     (NGRAPHS * C_DIM)   // 448
#define SCAN_CHUNK 1024
#define NCHUNK    45                  // ceil(1433/32)

// ---------- helpers ----------
__device__ __forceinline__ unsigned float_key(float f) {
    unsigned b = __float_as_uint(f);
    return (b & 0x80000000u) ? ~b : (b | 0x80000000u);
}
__device__ __forceinline__ float key_float(unsigned u) {
    unsigned b = (u & 0x80000000u) ? (u ^ 0x80000000u) : ~u;
    return __uint_as_float(b);
}

// async global->LDS, 4 bytes per lane, LDS dest = uniform base + lane*4
__device__ __forceinline__ void gll4(const float* gsrc, float* ldst) {
    __builtin_amdgcn_global_load_lds(
        (const __attribute__((address_space(1))) void*)gsrc,
        (__attribute__((address_space(3))) void*)ldst, 4, 0, 0);
}

// ---------- in-degree count (int atomics), deg pre-zeroed ----------
__global__ void k_deg(const int* __restrict__ dst, int* __restrict__ deg, int E) {
    int i = blockIdx.x * 256 + threadIdx.x;
    if (i < E) atomicAdd(&deg[dst[i]], 1);
}

// ---------- exclusive scan of deg -> cursor (3 kernels) ----------
__global__ void k_scan_block(const int* __restrict__ deg, int* __restrict__ cursor,
                             int* __restrict__ bsum, int n) {
    __shared__ int sh[256];
    int base = blockIdx.x * SCAN_CHUNK + threadIdx.x * 4;
    int v[4]; int sum = 0;
    #pragma unroll
    for (int j = 0; j < 4; ++j) { int idx = base + j; v[j] = (idx < n) ? deg[idx] : 0; sum += v[j]; }
    sh[threadIdx.x] = sum;
    __syncthreads();
    for (int off = 1; off < 256; off <<= 1) {
        int t = (threadIdx.x >= off) ? sh[threadIdx.x - off] : 0;
        __syncthreads();
        sh[threadIdx.x] += t;
        __syncthreads();
    }
    int excl = (threadIdx.x > 0) ? sh[threadIdx.x - 1] : 0;
    if (threadIdx.x == 255) bsum[blockIdx.x] = sh[255];
    int run = excl;
    #pragma unroll
    for (int j = 0; j < 4; ++j) { int idx = base + j; if (idx < n) cursor[idx] = run; run += v[j]; }
}

__global__ void k_scan_top(int* __restrict__ bsum, int nb) {
    __shared__ int sh[128];
    int v = (threadIdx.x < nb) ? bsum[threadIdx.x] : 0;
    sh[threadIdx.x] = v;
    __syncthreads();
    for (int off = 1; off < 128; off <<= 1) {
        int t = (threadIdx.x >= off) ? sh[threadIdx.x - off] : 0;
        __syncthreads();
        sh[threadIdx.x] += t;
        __syncthreads();
    }
    if (threadIdx.x < nb) bsum[threadIdx.x] = (threadIdx.x > 0) ? sh[threadIdx.x - 1] : 0;
}

__global__ void k_scan_add(int* __restrict__ cursor, const int* __restrict__ bsum, int n) {
    int i = blockIdx.x * 256 + threadIdx.x;
    if (i < n) cursor[i] += bsum[i >> 10];
}

// ---------- CSR fill: cursor mutates from start-offset to end-offset ----------
__global__ void k_fill(const int* __restrict__ ei, int* __restrict__ cursor,
                       int* __restrict__ csr, int E) {
    int e = blockIdx.x * 256 + threadIdx.x;
    if (e < E) {
        int s = ei[e], d = ei[E + e];
        int pos = atomicAdd(&cursor[d], 1);
        csr[pos] = s;
    }
}

// inv = rsqrt(deg + 1)
__global__ void k_inv(const int* __restrict__ deg, float* __restrict__ inv, int n) {
    int i = blockIdx.x * 256 + threadIdx.x;
    if (i < n) inv[i] = rsqrtf((float)deg[i] + 1.0f);
}

// ---------- GEMM1 v2: hs1[i][:] = (x[i,:] @ W1) * inv[i] ----------
// 1-wave blocks (64 threads), 64 rows/block -> 1563 blocks (~6.1/CU, 8 resident
// by LDS 20KB). Transposed x tile staged via global_load_lds (lane = row gather,
// LDS linear). Double-buffered, counted vmcnt(40), no barriers (wave-synchronous).
// Thread = 4 rows x 4 cols; per feature: 1 ds_read_b128 x (2-way bank, free) +
// 1 ds_read_b128 W (broadcast) + 16 FMA.
__device__ __forceinline__ void g1_stage(const float* __restrict__ x, size_t rowbase,
                                         const float* __restrict__ W1, int f0,
                                         float* xb, float* wb, int lane) {
    #pragma unroll
    for (int k = 0; k < 32; ++k) {
        int fc = f0 + k; fc = (fc < F_IN) ? fc : (F_IN - 1);   // col clamp (tail garbage killed by zeroed W)
        gll4(x + rowbase + fc, xb + k * 64);
    }
    #pragma unroll
    for (int j = 0; j < 8; ++j) {
        int wi = f0 * 16 + j * 64 + lane;
        wi = (wi < F_IN * 16) ? wi : (F_IN * 16 - 1);          // clamp, tail rows zeroed before use
        gll4(W1 + wi, wb + j * 64);
    }
}

__global__ __launch_bounds__(64, 2) void k_gemm1(const float* __restrict__ x,
                                                 const float* __restrict__ W1,
                                                 const float* __restrict__ inv,
                                                 float* __restrict__ hs1, int n) {
    __shared__ __align__(16) float xbuf[2][32 * 64];   // [buf][c*64 + row]  8KB each
    __shared__ __align__(16) float wbuf[2][32 * 16];   // [buf][ff*16 + c]   2KB each
    const int lane = threadIdx.x;
    const int r0 = blockIdx.x * 64;
    const int rg = lane >> 2, cg = lane & 3;
    int myrow = r0 + lane; if (myrow > n - 1) myrow = n - 1;   // row clamp: garbage -> discarded rows
    const size_t rowbase = (size_t)myrow * F_IN;

    float acc[4][4] = {};

    g1_stage(x, rowbase, W1, 0, xbuf[0], wbuf[0], lane);
    g1_stage(x, rowbase, W1, 32, xbuf[1], wbuf[1], lane);

    #pragma unroll 1
    for (int kc = 0; kc < NCHUNK; ++kc) {
        const int b = kc & 1;
        if (kc + 1 < NCHUNK) {
            asm volatile("s_waitcnt vmcnt(40)" ::: "memory");   // chunk kc landed, kc+1 in flight
        } else {
            asm volatile("s_waitcnt vmcnt(0)" ::: "memory");
        }
        const int f0 = kc * 32;
        if (f0 + 32 > F_IN) {
            // zero W rows for ff >= F_IN - f0 (kills tail-column garbage products)
            int nval = (F_IN - f0) * 16;                        // 400
            for (int t = nval + lane; t < 512; t += 64) wbuf[b][t] = 0.0f;
        }
        #pragma unroll
        for (int ff = 0; ff < 32; ++ff) {
            float4 xv = *reinterpret_cast<const float4*>(&xbuf[b][ff * 64 + (rg << 2)]);
            float4 wv = *reinterpret_cast<const float4*>(&wbuf[b][ff * 16 + (cg << 2)]);
            float xa[4] = {xv.x, xv.y, xv.z, xv.w};
            #pragma unroll
            for (int i2 = 0; i2 < 4; ++i2) {
                acc[i2][0] = fmaf(xa[i2], wv.x, acc[i2][0]);
                acc[i2][1] = fmaf(xa[i2], wv.y, acc[i2][1]);
                acc[i2][2] = fmaf(xa[i2], wv.z, acc[i2][2]);
                acc[i2][3] = fmaf(xa[i2], wv.w, acc[i2][3]);
            }
        }
        if (kc + 2 < NCHUNK) g1_stage(x, rowbase, W1, (kc + 2) * 32, xbuf[b], wbuf[b], lane);
    }

    #pragma unroll
    for (int i2 = 0; i2 < 4; ++i2) {
        int row = r0 + (rg << 2) + i2;
        if (row < n) {
            float s = inv[row];
            float4 v;
            v.x = acc[i2][0] * s; v.y = acc[i2][1] * s;
            v.z = acc[i2][2] * s; v.w = acc[i2][3] * s;
            *reinterpret_cast<float4*>(&hs1[(size_t)row * 16 + (cg << 2)]) = v;
        }
    }
}

// ---------- layer1 gather + relu + layer2 linear ----------
// 64 nodes/block, 4 lanes/node, float4 gathers, 4-deep csr pipeline.
__global__ __launch_bounds__(256) void k_agg1(const float* __restrict__ hs1,
                                              const int* __restrict__ cursor,
                                              const int* __restrict__ deg,
                                              const int* __restrict__ csr,
                                              const float* __restrict__ inv,
                                              const float* __restrict__ b1,
                                              const float* __restrict__ W2,
                                              float* __restrict__ hs2, int n) {
    __shared__ float sh[64][17];
    __shared__ float sW[112];
    __shared__ float sb[16];
    if (threadIdx.x < 112) sW[threadIdx.x] = W2[threadIdx.x];
    if (threadIdx.x < 16)  sb[threadIdx.x] = b1[threadIdx.x];
    __syncthreads();
    const int nl = threadIdx.x >> 2;      // node lane 0..63
    const int fq = threadIdx.x & 3;       // feature quad 0..3
    const int i = blockIdx.x * 64 + nl;
    if (i < n) {
        float4 acc = *(const float4*)&hs1[(size_t)i * 16 + fq * 4];  // self-loop (pre-scaled)
        const int en = cursor[i];
        int j = en - deg[i];
        for (; j + 4 <= en; j += 4) {
            int s0 = csr[j], s1 = csr[j + 1], s2 = csr[j + 2], s3 = csr[j + 3];
            float4 v0 = *(const float4*)&hs1[(size_t)s0 * 16 + fq * 4];
            float4 v1 = *(const float4*)&hs1[(size_t)s1 * 16 + fq * 4];
            float4 v2 = *(const float4*)&hs1[(size_t)s2 * 16 + fq * 4];
            float4 v3 = *(const float4*)&hs1[(size_t)s3 * 16 + fq * 4];
            acc.x += (v0.x + v1.x) + (v2.x + v3.x);
            acc.y += (v0.y + v1.y) + (v2.y + v3.y);
            acc.z += (v0.z + v1.z) + (v2.z + v3.z);
            acc.w += (v0.w + v1.w) + (v2.w + v3.w);
        }
        for (; j < en; ++j) {
            int s2i = csr[j];
            float4 v = *(const float4*)&hs1[(size_t)s2i * 16 + fq * 4];
            acc.x += v.x; acc.y += v.y; acc.z += v.z; acc.w += v.w;
        }
        float s = inv[i];
        sh[nl][fq * 4 + 0] = fmaxf(fmaf(acc.x, s, sb[fq * 4 + 0]), 0.0f);
        sh[nl][fq * 4 + 1] = fmaxf(fmaf(acc.y, s, sb[fq * 4 + 1]), 0.0f);
        sh[nl][fq * 4 + 2] = fmaxf(fmaf(acc.z, s, sb[fq * 4 + 2]), 0.0f);
        sh[nl][fq * 4 + 3] = fmaxf(fmaf(acc.w, s, sb[fq * 4 + 3]), 0.0f);
    }
    __syncthreads();
    for (int t = threadIdx.x; t < 64 * 7; t += 256) {
        int nl2 = t / 7, k = t % 7;
        int i2 = blockIdx.x * 64 + nl2;
        if (i2 < n) {
            float o = 0.0f;
            #pragma unroll
            for (int j = 0; j < 16; ++j) o = fmaf(sh[nl2][j], sW[j * 7 + k], o);
            hs2[(size_t)i2 * 7 + k] = o * inv[i2];
        }
    }
}

// ---------- layer2 gather + bias + log_softmax + graph max-pool ----------
__global__ __launch_bounds__(256) void k_agg2(const float* __restrict__ hs2,
                                              const int* __restrict__ cursor,
                                              const int* __restrict__ deg,
                                              const int* __restrict__ csr,
                                              const float* __restrict__ inv,
                                              const float* __restrict__ b2,
                                              const int* __restrict__ batch,
                                              float* __restrict__ out,
                                              unsigned* __restrict__ gkeys, int n) {
    __shared__ unsigned lmax[GPOOL];
    for (int t = threadIdx.x; t < GPOOL; t += 256) lmax[t] = 0u;
    __syncthreads();
    const int nl = threadIdx.x >> 3, k = threadIdx.x & 7;
    const int i = blockIdx.x * 32 + nl;
    if (i < n) {
        float z = -INFINITY;
        if (k < 7) {
            float acc = hs2[(size_t)i * 7 + k];    // self-loop (pre-scaled)
            const int en = cursor[i];
            int j = en - deg[i];
            for (; j + 4 <= en; j += 4) {
                int s0 = csr[j], s1 = csr[j + 1], s2 = csr[j + 2], s3 = csr[j + 3];
                float a0 = hs2[(size_t)s0 * 7 + k];
                float a1 = hs2[(size_t)s1 * 7 + k];
                float a2 = hs2[(size_t)s2 * 7 + k];
                float a3 = hs2[(size_t)s3 * 7 + k];
                acc += (a0 + a1) + (a2 + a3);
            }
            for (; j < en; ++j) acc += hs2[(size_t)csr[j] * 7 + k];
            z = fmaf(acc, inv[i], b2[k]);
        }
        float m = z;
        #pragma unroll
        for (int off = 4; off >= 1; off >>= 1) m = fmaxf(m, __shfl_xor(m, off, 8));
        float e = (k < 7) ? expf(z - m) : 0.0f;
        float ssum = e;
        #pragma unroll
        for (int off = 4; off >= 1; off >>= 1) ssum += __shfl_xor(ssum, off, 8);
        float l = logf(ssum);
        if (k < 7) {
            out[GPOOL + (size_t)i * 7 + k] = z - m - l;
            int b = batch[i];
            atomicMax(&lmax[b * 7 + k], float_key(z));
        }
    }
    __syncthreads();
    for (int t = threadIdx.x; t < GPOOL; t += 256) {
        unsigned v = lmax[t];
        if (v) atomicMax(&gkeys[t], v);
    }
}

__global__ void k_decode(const unsigned* __restrict__ gkeys, float* __restrict__ out) {
    int t = blockIdx.x * 64 + threadIdx.x;
    if (t < GPOOL) out[t] = key_float(gkeys[t]);
}

extern "C" void kernel_launch(void* const* d_in, const int* in_sizes, int n_in,
                              void* d_out, int out_size, void* d_ws, size_t ws_size,
                              hipStream_t stream) {
    const float* x    = (const float*)d_in[0];
    const int*   ei   = (const int*)d_in[1];
    const int*   batch= (const int*)d_in[2];
    const float* W1   = (const float*)d_in[3];
    const float* b1   = (const float*)d_in[4];
    const float* W2   = (const float*)d_in[5];
    const float* b2   = (const float*)d_in[6];
    float* out = (float*)d_out;
    const int E = in_sizes[1] / 2;
    const int n = in_sizes[0] / F_IN;
    const int nb = (n + SCAN_CHUNK - 1) / SCAN_CHUNK;   // 98

    // workspace: deg(int n) | cursor(int n) | bsum(int 128) | csr(int E) |
    //            inv(f n) | hs1(f 16n) | hs2(f 7n) | gkeys(u32 448)
    int* deg    = (int*)d_ws;
    int* cursor = deg + n;
    int* bsum   = cursor + n;
    int* csr    = bsum + 128;
    float* inv  = (float*)(csr + E);
    float* hs1  = inv + n;
    float* hs2  = hs1 + (size_t)n * 16;
    unsigned* gkeys = (unsigned*)(hs2 + (size_t)n * 7);

    hipMemsetAsync(deg, 0, (size_t)n * sizeof(int), stream);
    hipMemsetAsync(gkeys, 0, GPOOL * sizeof(unsigned), stream);

    k_deg<<<(E + 255) / 256, 256, 0, stream>>>(ei + E, deg, E);
    k_scan_block<<<nb, 256, 0, stream>>>(deg, cursor, bsum, n);
    k_scan_top<<<1, 128, 0, stream>>>(bsum, nb);
    k_scan_add<<<(n + 255) / 256, 256, 0, stream>>>(cursor, bsum, n);
    k_fill<<<(E + 255) / 256, 256, 0, stream>>>(ei, cursor, csr, E);
    k_inv<<<(n + 255) / 256, 256, 0, stream>>>(deg, inv, n);
    k_gemm1<<<(n + 63) / 64, 64, 0, stream>>>(x, W1, inv, hs1, n);
    k_agg1<<<(n + 63) / 64, 256, 0, stream>>>(hs1, cursor, deg, csr, inv, b1, W2, hs2, n);
    k_agg2<<<(n + 31) / 32, 256, 0, stream>>>(hs2, cursor, deg, csr, inv, b2, batch, out, gkeys, n);
    k_decode<<<7, 64, 0, stream>>>(gkeys, out);
}

// Round 4
// 1295.046 us; speedup vs baseline: 1.4091x; 1.3682x over previous
//
#include <hip/hip_runtime.h>
#include <hip/hip_bf16.h>
#include <math.h>

#define N_NODES   100000
#define F_IN      1433
#define H_DIM     16
#define C_DIM     7
#define NGRAPHS   64
#define GPOOL     (NGRAPHS * C_DIM)   // 448
#define SCAN_CHUNK 1024
#define NCHUNK    45                  // ceil(1433/32)
#define XSTRIDE   36                  // LDS row stride (floats): 32 data + 4 pad, 16B-aligned rows

// ---------- helpers ----------
__device__ __forceinline__ unsigned float_key(float f) {
    unsigned b = __float_as_uint(f);
    return (b & 0x80000000u) ? ~b : (b | 0x80000000u);
}
__device__ __forceinline__ float key_float(unsigned u) {
    unsigned b = (u & 0x80000000u) ? (u ^ 0x80000000u) : ~u;
    return __uint_as_float(b);
}

// ---------- in-degree count (int atomics), deg pre-zeroed ----------
__global__ void k_deg(const int* __restrict__ dst, int* __restrict__ deg, int E) {
    int i = blockIdx.x * 256 + threadIdx.x;
    if (i < E) atomicAdd(&deg[dst[i]], 1);
}

// ---------- exclusive scan of deg -> cursor (3 kernels) ----------
__global__ void k_scan_block(const int* __restrict__ deg, int* __restrict__ cursor,
                             int* __restrict__ bsum, int n) {
    __shared__ int sh[256];
    int base = blockIdx.x * SCAN_CHUNK + threadIdx.x * 4;
    int v[4]; int sum = 0;
    #pragma unroll
    for (int j = 0; j < 4; ++j) { int idx = base + j; v[j] = (idx < n) ? deg[idx] : 0; sum += v[j]; }
    sh[threadIdx.x] = sum;
    __syncthreads();
    for (int off = 1; off < 256; off <<= 1) {
        int t = (threadIdx.x >= off) ? sh[threadIdx.x - off] : 0;
        __syncthreads();
        sh[threadIdx.x] += t;
        __syncthreads();
    }
    int excl = (threadIdx.x > 0) ? sh[threadIdx.x - 1] : 0;
    if (threadIdx.x == 255) bsum[blockIdx.x] = sh[255];
    int run = excl;
    #pragma unroll
    for (int j = 0; j < 4; ++j) { int idx = base + j; if (idx < n) cursor[idx] = run; run += v[j]; }
}

__global__ void k_scan_top(int* __restrict__ bsum, int nb) {
    __shared__ int sh[128];
    int v = (threadIdx.x < nb) ? bsum[threadIdx.x] : 0;
    sh[threadIdx.x] = v;
    __syncthreads();
    for (int off = 1; off < 128; off <<= 1) {
        int t = (threadIdx.x >= off) ? sh[threadIdx.x - off] : 0;
        __syncthreads();
        sh[threadIdx.x] += t;
        __syncthreads();
    }
    if (threadIdx.x < nb) bsum[threadIdx.x] = (threadIdx.x > 0) ? sh[threadIdx.x - 1] : 0;
}

__global__ void k_scan_add(int* __restrict__ cursor, const int* __restrict__ bsum, int n) {
    int i = blockIdx.x * 256 + threadIdx.x;
    if (i < n) cursor[i] += bsum[i >> 10];
}

// ---------- CSR fill: cursor mutates from start-offset to end-offset ----------
__global__ void k_fill(const int* __restrict__ ei, int* __restrict__ cursor,
                       int* __restrict__ csr, int E) {
    int e = blockIdx.x * 256 + threadIdx.x;
    if (e < E) {
        int s = ei[e], d = ei[E + e];
        int pos = atomicAdd(&cursor[d], 1);
        csr[pos] = s;
    }
}

// inv = rsqrt(deg + 1)
__global__ void k_inv(const int* __restrict__ deg, float* __restrict__ inv, int n) {
    int i = blockIdx.x * 256 + threadIdx.x;
    if (i < n) inv[i] = rsqrtf((float)deg[i] + 1.0f);
}

// ---------- GEMM1 v3: hs1[i][:] = (x[i,:] @ W1) * inv[i] ----------
// 1-wave blocks, 64 rows/block, lane t owns row t. x staged COALESCED into
// row-major LDS [64][36] with XOR-swizzled 16B slots; W1 read via wave-uniform
// indices (compiler scalarizes to s_load -> SGPR operand in v_fma). All lanes
// compute the same k simultaneously -> zero transpose, zero gather.
// Per chunk/wave: 32 coalesced dword loads + 16 ds_write_b64 + 8 ds_read_b128
// + 512 FMA. Single LDS buffer, wave-synchronous (no barriers), loads for
// chunk c+1 issued before compute of chunk c.
__global__ __launch_bounds__(64, 4) void k_gemm1(const float* __restrict__ x,
                                                 const float* __restrict__ W1,
                                                 const float* __restrict__ inv,
                                                 float* __restrict__ hs1, int n) {
    __shared__ __align__(16) float xs[64 * XSTRIDE];   // 9.2 KB
    const int lane = threadIdx.x;
    const int r0 = blockIdx.x * 64;
    // staging map: per it (0..15), thread covers (row = it*4 + (lane>>4),
    // cols c0 = (lane&15)*2, c0+1). Global loads: 2 dwords, 256B-coalesced pairs.
    const int s_rowoff = lane >> 4;          // 0..3
    const int s_c0     = (lane & 15) * 2;    // 0,2,..,30
    const bool fast = (r0 + 64 <= n);
    const int rowclamp = n - 1;

    // LDS write offsets (float units), swizzle: slot (col>>2) ^ (row>>3)
    int woff[16];
    #pragma unroll
    for (int it = 0; it < 16; ++it) {
        int row = it * 4 + s_rowoff;
        int slot = (s_c0 >> 2) ^ (row >> 3);
        woff[it] = row * XSTRIDE + slot * 4 + (s_c0 & 3);
    }

    float rg[32];   // staged chunk (2 cols x 16 its)

    // ---- prologue: issue loads for chunk 0 ----
    {
        const int kbase = 0;
        #pragma unroll
        for (int it = 0; it < 16; ++it) {
            int row = r0 + it * 4 + s_rowoff;
            if (!fast) row = min(row, rowclamp);
            size_t b = (size_t)row * F_IN + kbase + s_c0;
            rg[it * 2 + 0] = x[b];
            rg[it * 2 + 1] = x[b + 1];
        }
    }

    float acc[16] = {};

    #pragma unroll 1
    for (int c = 0; c < NCHUNK; ++c) {
        const int kbase = c * 32;
        // ---- ds_write chunk c (with tail zeroing) ----
        const bool tail = (kbase + 32 > F_IN);
        #pragma unroll
        for (int it = 0; it < 16; ++it) {
            float v0 = rg[it * 2 + 0], v1 = rg[it * 2 + 1];
            if (tail) {
                if (kbase + s_c0     >= F_IN) v0 = 0.0f;
                if (kbase + s_c0 + 1 >= F_IN) v1 = 0.0f;
            }
            float2 p; p.x = v0; p.y = v1;
            *reinterpret_cast<float2*>(&xs[woff[it]]) = p;
        }
        // ---- issue loads for chunk c+1 ----
        if (c + 1 < NCHUNK) {
            const int kb2 = kbase + 32;
            #pragma unroll
            for (int it = 0; it < 16; ++it) {
                int row = r0 + it * 4 + s_rowoff;
                if (!fast) row = min(row, rowclamp);
                int col = kb2 + s_c0;
                int colc = min(col, F_IN - 2);        // clamp (tail garbage zeroed at write)
                size_t b = (size_t)row * F_IN + colc;
                rg[it * 2 + 0] = x[b];
                rg[it * 2 + 1] = x[b + 1];
            }
        }
        __builtin_amdgcn_sched_barrier(0);   // pin: stage-issue before compute
        // ---- compute chunk c: lane t = row t, uniform k, W from SGPRs ----
        #pragma unroll
        for (int g = 0; g < 8; ++g) {
            int rslot = g ^ (lane >> 3);
            float4 xv = *reinterpret_cast<const float4*>(&xs[lane * XSTRIDE + rslot * 4]);
            float xa[4] = {xv.x, xv.y, xv.z, xv.w};
            #pragma unroll
            for (int j = 0; j < 4; ++j) {
                int kk = kbase + g * 4 + j;
                kk = (kk < F_IN) ? kk : (F_IN - 1);    // uniform clamp (x already 0 there)
                const float* __restrict__ wr = W1 + (size_t)kk * 16;
                #pragma unroll
                for (int cc = 0; cc < 16; ++cc)
                    acc[cc] = fmaf(xa[j], wr[cc], acc[cc]);
            }
        }
    }

    // ---- epilogue: scale by inv, store 16 floats ----
    const int row = r0 + lane;
    if (row < n) {
        float s = inv[row];
        #pragma unroll
        for (int q = 0; q < 4; ++q) {
            float4 v;
            v.x = acc[q * 4 + 0] * s; v.y = acc[q * 4 + 1] * s;
            v.z = acc[q * 4 + 2] * s; v.w = acc[q * 4 + 3] * s;
            *reinterpret_cast<float4*>(&hs1[(size_t)row * 16 + q * 4]) = v;
        }
    }
}

// ---------- layer1 gather + relu + layer2 linear ----------
// 64 nodes/block, 4 lanes/node, float4 gathers, 4-deep csr pipeline.
__global__ __launch_bounds__(256) void k_agg1(const float* __restrict__ hs1,
                                              const int* __restrict__ cursor,
                                              const int* __restrict__ deg,
                                              const int* __restrict__ csr,
                                              const float* __restrict__ inv,
                                              const float* __restrict__ b1,
                                              const float* __restrict__ W2,
                                              float* __restrict__ hs2, int n) {
    __shared__ float sh[64][17];
    __shared__ float sW[112];
    __shared__ float sb[16];
    if (threadIdx.x < 112) sW[threadIdx.x] = W2[threadIdx.x];
    if (threadIdx.x < 16)  sb[threadIdx.x] = b1[threadIdx.x];
    __syncthreads();
    const int nl = threadIdx.x >> 2;      // node lane 0..63
    const int fq = threadIdx.x & 3;       // feature quad 0..3
    const int i = blockIdx.x * 64 + nl;
    if (i < n) {
        float4 acc = *(const float4*)&hs1[(size_t)i * 16 + fq * 4];  // self-loop (pre-scaled)
        const int en = cursor[i];
        int j = en - deg[i];
        for (; j + 4 <= en; j += 4) {
            int s0 = csr[j], s1 = csr[j + 1], s2 = csr[j + 2], s3 = csr[j + 3];
            float4 v0 = *(const float4*)&hs1[(size_t)s0 * 16 + fq * 4];
            float4 v1 = *(const float4*)&hs1[(size_t)s1 * 16 + fq * 4];
            float4 v2 = *(const float4*)&hs1[(size_t)s2 * 16 + fq * 4];
            float4 v3 = *(const float4*)&hs1[(size_t)s3 * 16 + fq * 4];
            acc.x += (v0.x + v1.x) + (v2.x + v3.x);
            acc.y += (v0.y + v1.y) + (v2.y + v3.y);
            acc.z += (v0.z + v1.z) + (v2.z + v3.z);
            acc.w += (v0.w + v1.w) + (v2.w + v3.w);
        }
        for (; j < en; ++j) {
            int s2i = csr[j];
            float4 v = *(const float4*)&hs1[(size_t)s2i * 16 + fq * 4];
            acc.x += v.x; acc.y += v.y; acc.z += v.z; acc.w += v.w;
        }
        float s = inv[i];
        sh[nl][fq * 4 + 0] = fmaxf(fmaf(acc.x, s, sb[fq * 4 + 0]), 0.0f);
        sh[nl][fq * 4 + 1] = fmaxf(fmaf(acc.y, s, sb[fq * 4 + 1]), 0.0f);
        sh[nl][fq * 4 + 2] = fmaxf(fmaf(acc.z, s, sb[fq * 4 + 2]), 0.0f);
        sh[nl][fq * 4 + 3] = fmaxf(fmaf(acc.w, s, sb[fq * 4 + 3]), 0.0f);
    }
    __syncthreads();
    for (int t = threadIdx.x; t < 64 * 7; t += 256) {
        int nl2 = t / 7, k = t % 7;
        int i2 = blockIdx.x * 64 + nl2;
        if (i2 < n) {
            float o = 0.0f;
            #pragma unroll
            for (int j = 0; j < 16; ++j) o = fmaf(sh[nl2][j], sW[j * 7 + k], o);
            hs2[(size_t)i2 * 7 + k] = o * inv[i2];
        }
    }
}

// ---------- layer2 gather + bias + log_softmax + graph max-pool ----------
__global__ __launch_bounds__(256) void k_agg2(const float* __restrict__ hs2,
                                              const int* __restrict__ cursor,
                                              const int* __restrict__ deg,
                                              const int* __restrict__ csr,
                                              const float* __restrict__ inv,
                                              const float* __restrict__ b2,
                                              const int* __restrict__ batch,
                                              float* __restrict__ out,
                                              unsigned* __restrict__ gkeys, int n) {
    __shared__ unsigned lmax[GPOOL];
    for (int t = threadIdx.x; t < GPOOL; t += 256) lmax[t] = 0u;
    __syncthreads();
    const int nl = threadIdx.x >> 3, k = threadIdx.x & 7;
    const int i = blockIdx.x * 32 + nl;
    if (i < n) {
        float z = -INFINITY;
        if (k < 7) {
            float acc = hs2[(size_t)i * 7 + k];    // self-loop (pre-scaled)
            const int en = cursor[i];
            int j = en - deg[i];
            for (; j + 4 <= en; j += 4) {
                int s0 = csr[j], s1 = csr[j + 1], s2 = csr[j + 2], s3 = csr[j + 3];
                float a0 = hs2[(size_t)s0 * 7 + k];
                float a1 = hs2[(size_t)s1 * 7 + k];
                float a2 = hs2[(size_t)s2 * 7 + k];
                float a3 = hs2[(size_t)s3 * 7 + k];
                acc += (a0 + a1) + (a2 + a3);
            }
            for (; j < en; ++j) acc += hs2[(size_t)csr[j] * 7 + k];
            z = fmaf(acc, inv[i], b2[k]);
        }
        float m = z;
        #pragma unroll
        for (int off = 4; off >= 1; off >>= 1) m = fmaxf(m, __shfl_xor(m, off, 8));
        float e = (k < 7) ? expf(z - m) : 0.0f;
        float ssum = e;
        #pragma unroll
        for (int off = 4; off >= 1; off >>= 1) ssum += __shfl_xor(ssum, off, 8);
        float l = logf(ssum);
        if (k < 7) {
            out[GPOOL + (size_t)i * 7 + k] = z - m - l;
            int b = batch[i];
            atomicMax(&lmax[b * 7 + k], float_key(z));
        }
    }
    __syncthreads();
    for (int t = threadIdx.x; t < GPOOL; t += 256) {
        unsigned v = lmax[t];
        if (v) atomicMax(&gkeys[t], v);
    }
}

__global__ void k_decode(const unsigned* __restrict__ gkeys, float* __restrict__ out) {
    int t = blockIdx.x * 64 + threadIdx.x;
    if (t < GPOOL) out[t] = key_float(gkeys[t]);
}

extern "C" void kernel_launch(void* const* d_in, const int* in_sizes, int n_in,
                              void* d_out, int out_size, void* d_ws, size_t ws_size,
                              hipStream_t stream) {
    const float* x    = (const float*)d_in[0];
    const int*   ei   = (const int*)d_in[1];
    const int*   batch= (const int*)d_in[2];
    const float* W1   = (const float*)d_in[3];
    const float* b1   = (const float*)d_in[4];
    const float* W2   = (const float*)d_in[5];
    const float* b2   = (const float*)d_in[6];
    float* out = (float*)d_out;
    const int E = in_sizes[1] / 2;
    const int n = in_sizes[0] / F_IN;
    const int nb = (n + SCAN_CHUNK - 1) / SCAN_CHUNK;   // 98

    // workspace: deg(int n) | cursor(int n) | bsum(int 128) | csr(int E) |
    //            inv(f n) | hs1(f 16n) | hs2(f 7n) | gkeys(u32 448)
    int* deg    = (int*)d_ws;
    int* cursor = deg + n;
    int* bsum   = cursor + n;
    int* csr    = bsum + 128;
    float* inv  = (float*)(csr + E);
    float* hs1  = inv + n;
    float* hs2  = hs1 + (size_t)n * 16;
    unsigned* gkeys = (unsigned*)(hs2 + (size_t)n * 7);

    hipMemsetAsync(deg, 0, (size_t)n * sizeof(int), stream);
    hipMemsetAsync(gkeys, 0, GPOOL * sizeof(unsigned), stream);

    k_deg<<<(E + 255) / 256, 256, 0, stream>>>(ei + E, deg, E);
    k_scan_block<<<nb, 256, 0, stream>>>(deg, cursor, bsum, n);
    k_scan_top<<<1, 128, 0, stream>>>(bsum, nb);
    k_scan_add<<<(n + 255) / 256, 256, 0, stream>>>(cursor, bsum, n);
    k_fill<<<(E + 255) / 256, 256, 0, stream>>>(ei, cursor, csr, E);
    k_inv<<<(n + 255) / 256, 256, 0, stream>>>(deg, inv, n);
    k_gemm1<<<(n + 63) / 64, 64, 0, stream>>>(x, W1, inv, hs1, n);
    k_agg1<<<(n + 63) / 64, 256, 0, stream>>>(hs1, cursor, deg, csr, inv, b1, W2, hs2, n);
    k_agg2<<<(n + 31) / 32, 256, 0, stream>>>(hs2, cursor, deg, csr, inv, b2, batch, out, gkeys, n);
    k_decode<<<7, 64, 0, stream>>>(gkeys, out);
}